// Round 9
// baseline (1486.488 us; speedup 1.0000x reference)
//
#include <hip/hip_runtime.h>
#include <math.h>

#define HID 384
#define SLEN 128
#define NB 512
#define MTOK (NB*SLEN)   // 65536 tokens
#define NLAB 32
#define NSLOT 128
#define APITCH 40        // LDS fp16 pitch: 16B-aligned rows

typedef _Float16 h8 __attribute__((ext_vector_type(8)));
typedef _Float16 h4v __attribute__((ext_vector_type(4)));
typedef __bf16   b8 __attribute__((ext_vector_type(8)));
typedef float    f4 __attribute__((ext_vector_type(4)));

// ---- NaN-proof primitives ----
__device__ __forceinline__ float sane(float x){
  return __builtin_isfinite(x) ? x : 0.f;
}
__device__ __forceinline__ float clampf(float x, float lo, float hi){
  return fminf(hi, fmaxf(lo, x));                      // NaN -> lo (finite)
}
__device__ __forceinline__ float fast_tanh(float x){
  x = clampf(x, -15.f, 15.f);
  float e = __expf(2.f * x);
  return (e - 1.f) / (e + 1.f);
}
__device__ __forceinline__ float sigmoid_c(float x){
  x = clampf(x, -60.f, 60.f);
  return 1.f / (1.f + __expf(-x));
}
__device__ __forceinline__ void split16(float x, _Float16* h, _Float16* l){
  _Float16 hh = (_Float16)x; *h = hh; *l = (_Float16)(x - (float)hh);
}
__device__ __forceinline__ h8 ldh(const _Float16* p){ return *reinterpret_cast<const h8*>(p); }
__device__ __forceinline__ b8 ldb(const __bf16* p){ return *reinterpret_cast<const b8*>(p); }
__device__ __forceinline__ f4 mfma16h(h8 a, h8 b, f4 c){
  return __builtin_amdgcn_mfma_f32_16x16x32_f16(a, b, c, 0, 0, 0);
}
__device__ __forceinline__ f4 mfma16b(b8 a, b8 b, f4 c){
  return __builtin_amdgcn_mfma_f32_16x16x32_bf16(a, b, c, 0, 0, 0);
}

// ---------------- setup kernels ----------------

__global__ void k_lens(const int* __restrict__ raw, int* __restrict__ lensN){
  const int b = threadIdx.x;          // block = NB = 512
  __shared__ int is64;
  if (b == 0) is64 = (raw[1] == 0) ? 1 : 0;
  __syncthreads();
  int v = is64 ? raw[2 * b] : raw[b];
  v = v < 0 ? 0 : (v > SLEN ? SLEN : v);
  lensN[b] = v;
}

// transposed fp16 hi/lo split
__global__ void k_wsplit16(const float* __restrict__ in, _Float16* __restrict__ outh,
                           _Float16* __restrict__ outl, int R, int C){
  int idx = blockIdx.x * blockDim.x + threadIdx.x;
  if (idx < R * C){
    int r = idx / C, c = idx - r * C;
    float v = sane(in[idx]);
    _Float16 h = (_Float16)v;
    outh[(size_t)c * R + r] = h;
    outl[(size_t)c * R + r] = (_Float16)(v - (float)h);
  }
}

// transposed bf16 hi/lo split (slot head weights)
__global__ void k_wsplitbf(const float* __restrict__ in, __bf16* __restrict__ outh,
                           __bf16* __restrict__ outl, int R, int C){
  int idx = blockIdx.x * blockDim.x + threadIdx.x;
  if (idx < R * C){
    int r = idx / C, c = idx - r * C;
    float v = sane(in[idx]);
    __bf16 h = (__bf16)v;
    outh[(size_t)c * R + r] = h;
    outl[(size_t)c * R + r] = (__bf16)(v - (float)h);
  }
}

__global__ void k_transpose32(const float* __restrict__ in, float* __restrict__ out,
                              int R, int C){
  int idx = blockIdx.x * blockDim.x + threadIdx.x;
  if (idx < R * C){ int r = idx / C, c = idx - r * C; out[(size_t)c * R + r] = sane(in[idx]); }
}

__global__ void k_w35(const float* __restrict__ W3, const float* __restrict__ W4,
                      const float* __restrict__ b4, const float* __restrict__ W5,
                      float* __restrict__ w35, float* __restrict__ w45, float* __restrict__ b45){
  __shared__ float w5s[HID];
  int t = threadIdx.x;                     // block = 384
  w5s[t] = sane(W5[t]);
  __syncthreads();
  float s3 = 0.f, s4 = 0.f;
  for (int j = 0; j < HID; ++j){
    float w5 = w5s[j];
    s3 += sane(W3[(size_t)t * HID + j]) * w5;
    s4 += sane(W4[(size_t)t * HID + j]) * w5;
  }
  w35[t] = s3; w45[t] = s4;
  if (t == 0){
    float s = 0.f;
    for (int j = 0; j < HID; ++j) s += sane(b4[j]) * w5s[j];
    *b45 = s;
  }
}

// X0 = split(tanh(Cs)) — setup, vectorized f4 -> 2x h4v
__global__ void k_prep(const float* __restrict__ Cs,
                       _Float16* __restrict__ X0h, _Float16* __restrict__ X0l){
  const size_t n4 = (size_t)MTOK * HID / 4;
  const size_t stride = (size_t)gridDim.x * blockDim.x;
  for (size_t i = blockIdx.x * (size_t)blockDim.x + threadIdx.x; i < n4; i += stride){
    f4 v = *(const f4*)(Cs + i * 4);
    h4v hh, ll;
#pragma unroll
    for (int j = 0; j < 4; ++j){
      float x = fast_tanh(sane(v[j]));
      _Float16 h = (_Float16)x;
      hh[j] = h; ll[j] = (_Float16)(x - (float)h);
    }
    *(h4v*)(X0h + i * 4) = hh;
    *(h4v*)(X0l + i * 4) = ll;
  }
}

__global__ void k_ci(const float* __restrict__ ci, float* __restrict__ r_inte){
  size_t i = blockIdx.x * (size_t)blockDim.x + threadIdx.x;
  if (i < (size_t)NB * HID) r_inte[i] = sane(ci[i]);
}

__global__ void k_hy(const float* __restrict__ Hm, const float* __restrict__ w45,
                     const float* __restrict__ b45, float* __restrict__ hy){
  int wave = threadIdx.x >> 6, lane = threadIdx.x & 63;
  int tok = blockIdx.x * 4 + wave;
  const float* row = Hm + (size_t)tok * HID;
  float s = 0.f;
#pragma unroll
  for (int i = 0; i < 6; ++i){ int k = lane + 64 * i; s += sane(row[k]) * w45[k]; }
  for (int off = 32; off; off >>= 1) s += __shfl_down(s, off);
  if (lane == 0) hy[tok] = clampf(s + *b45, -1e30f, 1e30f);
}

// ---------------- per-iteration small GEMMs (fp32) ----------------
template <int TANH>
__global__ void k_vecmat(const float* __restrict__ in, const float* __restrict__ Wt,
                         float* __restrict__ out, float* __restrict__ pre_store){
  const int b = blockIdx.x, t = threadIdx.x;   // block = 384
  __shared__ float v[HID];
  float x = in[(size_t)b * HID + t];
  if (TANH) x = fast_tanh(x);
  v[t] = x;
  if (pre_store) pre_store[(size_t)b * HID + t] = x;
  __syncthreads();
  const float* wr = Wt + (size_t)t * HID;
  float s = 0.f;
  for (int k = 0; k < HID; ++k) s += v[k] * wr[k];
  out[(size_t)b * HID + t] = clampf(s, -1e30f, 1e30f);
}

// T = split(tanh(P0 + yw1)) — per-iteration elementwise (tanh computed ONCE)
__global__ void k_T(const _Float16* __restrict__ P0h, const _Float16* __restrict__ P0l,
                    const float* __restrict__ yw1,
                    _Float16* __restrict__ Th, _Float16* __restrict__ Tl){
  const size_t n8 = (size_t)MTOK * HID / 8;
  const size_t stride = (size_t)gridDim.x * blockDim.x;
  for (size_t i = blockIdx.x * (size_t)blockDim.x + threadIdx.x; i < n8; i += stride){
    const unsigned int tok = (unsigned int)(i / 48u);        // HID/8 = 48
    const unsigned int c8  = ((unsigned int)i - tok * 48u) * 8u;
    const unsigned int b   = tok >> 7;                       // /SLEN
    h8 ph = ldh(P0h + i * 8);
    h8 pl = ldh(P0l + i * 8);
    const float* yw = yw1 + (size_t)b * HID + c8;
    h8 th, tl;
#pragma unroll
    for (int j = 0; j < 8; ++j){
      float x = fast_tanh((float)ph[j] + (float)pl[j] + yw[j]);
      _Float16 h = (_Float16)x;
      th[j] = h; tl[j] = (_Float16)(x - (float)h);
    }
    *(h8*)(Th + i * 8) = th;
    *(h8*)(Tl + i * 8) = tl;
  }
}

// ---------------- staged split-fp16 GEMM: P0 = X0 @ W0 (setup, copy staging) -----
__global__ void __launch_bounds__(256, 3) k_p0c(
    const _Float16* __restrict__ X0h, const _Float16* __restrict__ X0l,
    const _Float16* __restrict__ Wth, const _Float16* __restrict__ Wtl,
    const int* __restrict__ lens,
    _Float16* __restrict__ P0h, _Float16* __restrict__ P0l){
  __shared__ _Float16 Ah[128*APITCH], Al[128*APITCH], Bh[128*APITCH], Bl[128*APITCH];
  const int t = threadIdx.x;
  const int wave = t >> 6, lane = t & 63, quad = lane >> 4, lr = lane & 15;
  const int wm = wave & 1, wn = wave >> 1;
  const int bx = blockIdx.x, by = blockIdx.y;
  const int len = lens[bx];
  const bool live = (wm * 64) < len;
  f4 acc[4][4] = {};
  for (int kk = 0; kk < HID; kk += 32){
#pragma unroll
    for (int i = 0; i < 2; ++i){
      int tau = t + 256 * i;
      int row = tau >> 2, v8 = (tau & 3) << 3;
      size_t ga = ((size_t)(bx * 128 + row)) * HID + kk + v8;
      size_t gb = ((size_t)(by * 128 + row)) * HID + kk + v8;
      *(h8*)&Ah[row * APITCH + v8] = ldh(X0h + ga);
      *(h8*)&Al[row * APITCH + v8] = ldh(X0l + ga);
      *(h8*)&Bh[row * APITCH + v8] = ldh(Wth + gb);
      *(h8*)&Bl[row * APITCH + v8] = ldh(Wtl + gb);
    }
    __syncthreads();
    if (live){
      h8 ah[4], al[4];
#pragma unroll
      for (int mi = 0; mi < 4; ++mi){
        int r = (wm * 64 + mi * 16 + lr) * APITCH + quad * 8;
        ah[mi] = *(h8*)&Ah[r]; al[mi] = *(h8*)&Al[r];
      }
#pragma unroll
      for (int ni = 0; ni < 4; ++ni){
        int r = (wn * 64 + ni * 16 + lr) * APITCH + quad * 8;
        h8 bh = *(h8*)&Bh[r], bl = *(h8*)&Bl[r];
#pragma unroll
        for (int mi = 0; mi < 4; ++mi){
          acc[mi][ni] = mfma16h(ah[mi], bh, acc[mi][ni]);
          acc[mi][ni] = mfma16h(ah[mi], bl, acc[mi][ni]);
          acc[mi][ni] = mfma16h(al[mi], bh, acc[mi][ni]);
        }
      }
    }
    __syncthreads();
  }
  if (live){
#pragma unroll
    for (int ni = 0; ni < 4; ++ni){
      int col = by * 128 + wn * 64 + ni * 16 + lr;
#pragma unroll
      for (int mi = 0; mi < 4; ++mi)
#pragma unroll
        for (int r = 0; r < 4; ++r){
          int rl = wm * 64 + mi * 16 + quad * 4 + r;
          if (rl < len){
            size_t o = ((size_t)(bx * 128 + rl)) * HID + col;
            _Float16 h, l; split16(acc[mi][ni][r], &h, &l);
            P0h[o] = h; P0l[o] = l;
          }
        }
    }
  }
}

// ---------------- staged split-fp16 GEMM: G2 (per iteration, copy staging) -------
// f = sigmoid(T @ W2); epilogue: masked row-reduce of fusion_out -> atomicAdd S.
__global__ void __launch_bounds__(256, 3) k_g2c(
    const _Float16* __restrict__ Th, const _Float16* __restrict__ Tl,
    const _Float16* __restrict__ Wth, const _Float16* __restrict__ Wtl,
    const float* __restrict__ Cs, const float* __restrict__ y0b,
    const float* __restrict__ r_inte, const int* __restrict__ lens,
    float* __restrict__ S){
  __shared__ _Float16 Ah[128*APITCH], Al[128*APITCH], Bh[128*APITCH], Bl[128*APITCH];
  const int t = threadIdx.x;
  const int wave = t >> 6, lane = t & 63, quad = lane >> 4, lr = lane & 15;
  const int wm = wave & 1, wn = wave >> 1;
  const int bx = blockIdx.x, by = blockIdx.y;
  const int len = lens[bx];
  const bool live = (wm * 64) < len;
  f4 acc[4][4] = {};
  for (int kk = 0; kk < HID; kk += 32){
#pragma unroll
    for (int i = 0; i < 2; ++i){
      int tau = t + 256 * i;
      int row = tau >> 2, v8 = (tau & 3) << 3;
      size_t ga = ((size_t)(bx * 128 + row)) * HID + kk + v8;
      size_t gb = ((size_t)(by * 128 + row)) * HID + kk + v8;
      *(h8*)&Ah[row * APITCH + v8] = ldh(Th + ga);
      *(h8*)&Al[row * APITCH + v8] = ldh(Tl + ga);
      *(h8*)&Bh[row * APITCH + v8] = ldh(Wth + gb);
      *(h8*)&Bl[row * APITCH + v8] = ldh(Wtl + gb);
    }
    __syncthreads();
    if (live){
      h8 ah[4], al[4];
#pragma unroll
      for (int mi = 0; mi < 4; ++mi){
        int r = (wm * 64 + mi * 16 + lr) * APITCH + quad * 8;
        ah[mi] = *(h8*)&Ah[r]; al[mi] = *(h8*)&Al[r];
      }
#pragma unroll
      for (int ni = 0; ni < 4; ++ni){
        int r = (wn * 64 + ni * 16 + lr) * APITCH + quad * 8;
        h8 bh = *(h8*)&Bh[r], bl = *(h8*)&Bl[r];
#pragma unroll
        for (int mi = 0; mi < 4; ++mi){
          acc[mi][ni] = mfma16h(ah[mi], bh, acc[mi][ni]);
          acc[mi][ni] = mfma16h(ah[mi], bl, acc[mi][ni]);
          acc[mi][ni] = mfma16h(al[mi], bh, acc[mi][ni]);
        }
      }
    }
    __syncthreads();
  }
  if (live){
    const float* yb = y0b + (size_t)bx * HID;
    const float* rb = r_inte + (size_t)bx * HID;
#pragma unroll
    for (int ni = 0; ni < 4; ++ni){
      int col = by * 128 + wn * 64 + ni * 16 + lr;
      const float y0 = yb[col];
      const float yv = rb[col];
      float csum = 0.f;
#pragma unroll
      for (int mi = 0; mi < 4; ++mi)
#pragma unroll
        for (int r = 0; r < 4; ++r){
          int rl = wm * 64 + mi * 16 + quad * 4 + r;
          const float f = sigmoid_c(acc[mi][ni][r]);
          const float omf = 1.f - f;
          const float xv = sane(Cs[((size_t)(bx * 128 + rl)) * HID + col]);
          const float x0 = fast_tanh(xv);
          const float outv = f * f * x0 + f * xv + omf * omf * y0 + omf * yv;
          csum += (rl < len) ? outv : 0.f;
        }
      csum += __shfl_xor(csum, 16);
      csum += __shfl_xor(csum, 32);
      if (quad == 0) atomicAdd(&S[(size_t)bx * HID + col], csum);
    }
  }
}

// ---------------- stage D: rates -> softmax -> f_inte -> r_inte (fp32) ----------------
__global__ void k_stageD(
    const float* __restrict__ Cs, const float* __restrict__ Hm,
    const float* __restrict__ ci,
    const float* __restrict__ fss, const float* __restrict__ w35,
    const float* __restrict__ hy, const int* __restrict__ lens,
    float* __restrict__ r_inte){
  const int b = blockIdx.x;
  const int t = threadIdx.x;            // 384 threads = 6 waves
  const int len = lens[b];
  __shared__ float fssw[HID];
  __shared__ float rates[SLEN];
  __shared__ float wA[SLEN], wB[SLEN], wC[SLEN], wD[SLEN];
  fssw[t] = fss[(size_t)b * HID + t] * w35[t];
  __syncthreads();
  const int wave = t >> 6, lane = t & 63;
  for (int l = wave; l < SLEN; l += 6){
    const float* row = Cs + ((size_t)b * SLEN + l) * HID;
    float s = 0.f;
#pragma unroll
    for (int i = 0; i < 6; ++i){ int k = lane + 64 * i; s += sane(row[k]) * fssw[k]; }
    for (int off = 32; off; off >>= 1) s += __shfl_down(s, off);
    if (lane == 0) rates[l] = clampf(s + hy[(size_t)b * SLEN + l], -1e30f, 1e30f);
  }
  __syncthreads();
  if (wave == 0){
    float r0 = (lane < len) ? rates[lane] : -3.0e38f;
    float r1 = (lane + 64 < len) ? rates[lane + 64] : -3.0e38f;
    float mx = fmaxf(r0, r1);
    for (int off = 32; off; off >>= 1) mx = fmaxf(mx, __shfl_xor(mx, off));
    float e0 = (lane < len) ? __expf(r0 - mx) : 0.f;
    float e1 = (lane + 64 < len) ? __expf(r1 - mx) : 0.f;
    float sm = e0 + e1;
    for (int off = 32; off; off >>= 1) sm += __shfl_xor(sm, off);
    const float inv = (sm > 0.f) ? (1.f / sm) : 0.f;
    float a0 = clampf(e0 * inv, 0.f, 1.f), a1 = clampf(e1 * inv, 0.f, 1.f);
    wA[lane] = a0 * a0; wB[lane] = a0; wC[lane] = (1.f - a0) * (1.f - a0); wD[lane] = 1.f - a0;
    wA[lane + 64] = a1 * a1; wB[lane + 64] = a1;
    wC[lane + 64] = (1.f - a1) * (1.f - a1); wD[lane + 64] = 1.f - a1;
  }
  __syncthreads();
  const float fs = fss[(size_t)b * HID + t];
  float acc = 0.f;
  for (int l = 0; l < len; ++l){
    const float cv = sane(Cs[((size_t)b * SLEN + l) * HID + t]);
    const float hv = sane(Hm[((size_t)b * SLEN + l) * HID + t]);
    const float rs = fs * cv;
    acc += wA[l] * fast_tanh(rs) + wB[l] * rs + wC[l] * fast_tanh(hv) + wD[l] * hv;
  }
  r_inte[(size_t)b * HID + t] = clampf(acc + sane(ci[(size_t)b * HID + t]), -1e30f, 1e30f);
}

// ---------------- output heads (fp32 outputs) ----------------
__global__ void k_intent(const float* __restrict__ r_inte, const float* __restrict__ Wit,
                         float* __restrict__ out){
  const int t = threadIdx.x;                 // block 128: 4 sentences x 32 labels
  const int b = blockIdx.x * 4 + (t >> 5);
  const int n = t & 31;
  const float* wr = Wit + (size_t)n * HID;
  const float* rr = r_inte + (size_t)b * HID;
  float s = 0.f;
  for (int k = 0; k < HID; ++k) s += rr[k] * wr[k];
  out[(size_t)b * NLAB + n] = clampf(s, -3e38f, 3e38f);
}

// slot_output = [H | fss(b).*c] @ W_slot, split-bf16 3-product, dead waves write 0.
__global__ void __launch_bounds__(256, 2) k_slot_bf(
    const float* __restrict__ Hm, const float* __restrict__ Cs,
    const float* __restrict__ fss, const int* __restrict__ lens,
    const __bf16* __restrict__ Wth, const __bf16* __restrict__ Wtl,
    float* __restrict__ out){
  const int wave = threadIdx.x >> 6, lane = threadIdx.x & 63;
  const int quad = lane >> 4, lr = lane & 15;
  const int m0 = blockIdx.x * 128 + (wave & 1) * 64;
  const int n0 = (wave >> 1) * 64;
  const int b = blockIdx.x;
  const int ko = quad * 8;
  const int len = lens[b];
  if ((wave & 1) * 64 >= len){
#pragma unroll
    for (int mi = 0; mi < 4; ++mi)
#pragma unroll
      for (int ni = 0; ni < 4; ++ni)
#pragma unroll
        for (int r = 0; r < 4; ++r){
          const int row = m0 + mi * 16 + quad * 4 + r;
          const int col = n0 + ni * 16 + lr;
          out[(size_t)row * NSLOT + col] = 0.f;
        }
    return;
  }
  f4 acc[4][4] = {};
  for (int kk = 0; kk < 2 * HID; kk += 32){
    b8 ah[4], al[4], bh[4], bl[4];
#pragma unroll
    for (int i = 0; i < 4; ++i){
      size_t rb = (size_t)(n0 + i * 16 + lr) * (2 * HID) + kk + ko;
      bh[i] = ldb(Wth + rb); bl[i] = ldb(Wtl + rb);
    }
    if (kk < HID){
#pragma unroll
      for (int i = 0; i < 4; ++i){
        const float* hrow = Hm + (size_t)(m0 + i * 16 + lr) * HID + kk + ko;
        b8 vh, vl;
#pragma unroll
        for (int j = 0; j < 8; ++j){
          float v = sane(hrow[j]);
          __bf16 h = (__bf16)v;
          vh[j] = h; vl[j] = (__bf16)(v - (float)h);
        }
        ah[i] = vh; al[i] = vl;
      }
    } else {
      const int k2 = kk - HID + ko;
      float fv[8];
#pragma unroll
      for (int j = 0; j < 8; ++j) fv[j] = fss[(size_t)b * HID + k2 + j];
#pragma unroll
      for (int i = 0; i < 4; ++i){
        const float* crow = Cs + (size_t)(m0 + i * 16 + lr) * HID + k2;
        b8 vh, vl;
#pragma unroll
        for (int j = 0; j < 8; ++j){
          float v = fv[j] * sane(crow[j]);
          __bf16 h = (__bf16)v;
          vh[j] = h; vl[j] = (__bf16)(v - (float)h);
        }
        ah[i] = vh; al[i] = vl;
      }
    }
#pragma unroll
    for (int mi = 0; mi < 4; ++mi)
#pragma unroll
      for (int ni = 0; ni < 4; ++ni){
        acc[mi][ni] = mfma16b(ah[mi], bh[ni], acc[mi][ni]);
        acc[mi][ni] = mfma16b(ah[mi], bl[ni], acc[mi][ni]);
        acc[mi][ni] = mfma16b(al[mi], bh[ni], acc[mi][ni]);
      }
  }
#pragma unroll
  for (int mi = 0; mi < 4; ++mi)
#pragma unroll
    for (int ni = 0; ni < 4; ++ni)
#pragma unroll
      for (int r = 0; r < 4; ++r){
        const int row = m0 + mi * 16 + quad * 4 + r;
        const int col = n0 + ni * 16 + lr;
        out[(size_t)row * NSLOT + col] = clampf(acc[mi][ni][r], -3e38f, 3e38f);
      }
}

// ---------------- launch ----------------
extern "C" void kernel_launch(void* const* d_in, const int* in_sizes, int n_in,
                              void* d_out, int out_size, void* d_ws, size_t ws_size,
                              hipStream_t stream){
  (void)in_sizes; (void)n_in; (void)out_size;
  const float* Hm  = (const float*)d_in[0];
  const float* Cs  = (const float*)d_in[1];
  const float* ci  = (const float*)d_in[2];
  const float* W0  = (const float*)d_in[3];
  const float* W1  = (const float*)d_in[4];
  const float* W2  = (const float*)d_in[5];
  const float* W3  = (const float*)d_in[6];
  const float* W4  = (const float*)d_in[7];
  const float* b4  = (const float*)d_in[8];
  const float* W5  = (const float*)d_in[9];
  const float* Vs  = (const float*)d_in[10];
  const float* Wi  = (const float*)d_in[11];
  const float* Wsl = (const float*)d_in[12];
  const int* lens_raw = (const int*)d_in[13];
  // d_in[14] = iteration_num = 3 (hard-coded)

  char* base = (char*)d_ws;
  size_t off = 0;
  auto alloc = [&](size_t bytes) -> void* {
    void* p = base + off; off += (bytes + 255) & ~(size_t)255; return p;
  };
  const size_t NT = (size_t)MTOK * HID;
  _Float16* X0h  = (_Float16*)alloc(NT * 2);      // aliased as Th after k_p0c
  _Float16* X0l  = (_Float16*)alloc(NT * 2);      // aliased as Tl after k_p0c
  _Float16* P0h  = (_Float16*)alloc(NT * 2);
  _Float16* P0l  = (_Float16*)alloc(NT * 2);
  _Float16* W0th = (_Float16*)alloc((size_t)HID * HID * 2);
  _Float16* W0tl = (_Float16*)alloc((size_t)HID * HID * 2);
  _Float16* W2th = (_Float16*)alloc((size_t)HID * HID * 2);
  _Float16* W2tl = (_Float16*)alloc((size_t)HID * HID * 2);
  __bf16*   Wsth = (__bf16*)alloc((size_t)2 * HID * NSLOT * 2);
  __bf16*   Wstl = (__bf16*)alloc((size_t)2 * HID * NSLOT * 2);
  float* W1t    = (float*)alloc((size_t)HID * HID * 4);
  float* Vst    = (float*)alloc((size_t)HID * HID * 4);
  float* Wit    = (float*)alloc((size_t)HID * NLAB * 4);
  float* w35    = (float*)alloc(HID * 4);
  float* w45    = (float*)alloc(HID * 4);
  float* b45    = (float*)alloc(4);
  float* hy     = (float*)alloc((size_t)MTOK * 4);
  float* yw1    = (float*)alloc((size_t)NB * HID * 4);
  float* y0b    = (float*)alloc((size_t)NB * HID * 4);
  float* r_inte = (float*)alloc((size_t)NB * HID * 4);
  float* S      = (float*)alloc((size_t)NB * HID * 4);
  float* fss    = (float*)alloc((size_t)NB * HID * 4);
  int* lensN    = (int*)alloc((size_t)NB * 4);
  if (off > ws_size) return;

  _Float16* Th = X0h;   // X0 is dead after k_p0c; reuse its storage for T
  _Float16* Tl = X0l;

  k_lens<<<1, NB, 0, stream>>>(lens_raw, lensN);
  k_wsplit16<<<(HID * HID + 255) / 256, 256, 0, stream>>>(W0, W0th, W0tl, HID, HID);
  k_wsplit16<<<(HID * HID + 255) / 256, 256, 0, stream>>>(W2, W2th, W2tl, HID, HID);
  k_wsplitbf<<<(2 * HID * NSLOT + 255) / 256, 256, 0, stream>>>(Wsl, Wsth, Wstl, 2 * HID, NSLOT);
  k_transpose32<<<(HID * HID + 255) / 256, 256, 0, stream>>>(W1, W1t, HID, HID);
  k_transpose32<<<(HID * HID + 255) / 256, 256, 0, stream>>>(Vs, Vst, HID, HID);
  k_transpose32<<<(HID * NLAB + 255) / 256, 256, 0, stream>>>(Wi, Wit, HID, NLAB);
  k_w35<<<1, HID, 0, stream>>>(W3, W4, b4, W5, w35, w45, b45);
  k_ci<<<(NB * HID + 255) / 256, 256, 0, stream>>>(ci, r_inte);
  k_hy<<<MTOK / 4, 256, 0, stream>>>(Hm, w45, b45, hy);
  k_prep<<<4096, 256, 0, stream>>>(Cs, X0h, X0l);
  k_p0c<<<dim3(NB, 3), 256, 0, stream>>>(X0h, X0l, W0th, W0tl, lensN, P0h, P0l);

  for (int it = 0; it < 3; ++it){
    k_vecmat<1><<<NB, HID, 0, stream>>>(r_inte, W1t, yw1, y0b);
    hipMemsetAsync(S, 0, (size_t)NB * HID * 4, stream);
    k_T<<<4096, 256, 0, stream>>>(P0h, P0l, yw1, Th, Tl);
    k_g2c<<<dim3(NB, 3), 256, 0, stream>>>(Th, Tl, W2th, W2tl, Cs, y0b, r_inte, lensN, S);
    k_vecmat<0><<<NB, HID, 0, stream>>>(S, Vst, fss, (float*)nullptr);
    k_stageD<<<NB, HID, 0, stream>>>(Cs, Hm, ci, fss, w35, hy, lensN, r_inte);
  }

  float* outp = (float*)d_out;
  k_intent<<<NB / 4, 128, 0, stream>>>(r_inte, Wit, outp);
  k_slot_bf<<<NB, 256, 0, stream>>>(Hm, Cs, fss, lensN, Wsth, Wstl, outp + (size_t)NB * NLAB);
}

// Round 10
// 1406.007 us; speedup vs baseline: 1.0572x; 1.0572x over previous
//
#include <hip/hip_runtime.h>
#include <math.h>

#define HID 384
#define SLEN 128
#define NB 512
#define MTOK (NB*SLEN)   // 65536 tokens
#define NLAB 32
#define NSLOT 128
#define APITCH 40        // LDS fp16 pitch: 16B-aligned rows

typedef _Float16 h8 __attribute__((ext_vector_type(8)));
typedef _Float16 h4v __attribute__((ext_vector_type(4)));
typedef __bf16   b8 __attribute__((ext_vector_type(8)));
typedef float    f4 __attribute__((ext_vector_type(4)));

// ---- NaN-proof primitives ----
__device__ __forceinline__ float sane(float x){
  return __builtin_isfinite(x) ? x : 0.f;
}
__device__ __forceinline__ float clampf(float x, float lo, float hi){
  return fminf(hi, fmaxf(lo, x));                      // NaN -> lo (finite)
}
__device__ __forceinline__ float fast_tanh(float x){
  x = clampf(x, -15.f, 15.f);
  float e = __expf(2.f * x);
  return (e - 1.f) / (e + 1.f);
}
__device__ __forceinline__ float sigmoid_c(float x){
  x = clampf(x, -60.f, 60.f);
  return 1.f / (1.f + __expf(-x));
}
__device__ __forceinline__ void split16(float x, _Float16* h, _Float16* l){
  _Float16 hh = (_Float16)x; *h = hh; *l = (_Float16)(x - (float)hh);
}
__device__ __forceinline__ h8 ldh(const _Float16* p){ return *reinterpret_cast<const h8*>(p); }
__device__ __forceinline__ b8 ldb(const __bf16* p){ return *reinterpret_cast<const b8*>(p); }
__device__ __forceinline__ f4 mfma16h(h8 a, h8 b, f4 c){
  return __builtin_amdgcn_mfma_f32_16x16x32_f16(a, b, c, 0, 0, 0);
}
__device__ __forceinline__ f4 mfma16b(b8 a, b8 b, f4 c){
  return __builtin_amdgcn_mfma_f32_16x16x32_bf16(a, b, c, 0, 0, 0);
}

// ---------------- setup kernels ----------------

__global__ void k_lens(const int* __restrict__ raw, int* __restrict__ lensN){
  const int b = threadIdx.x;          // block = NB = 512
  __shared__ int is64;
  if (b == 0) is64 = (raw[1] == 0) ? 1 : 0;
  __syncthreads();
  int v = is64 ? raw[2 * b] : raw[b];
  v = v < 0 ? 0 : (v > SLEN ? SLEN : v);
  lensN[b] = v;
}

// transposed fp16 hi/lo split
__global__ void k_wsplit16(const float* __restrict__ in, _Float16* __restrict__ outh,
                           _Float16* __restrict__ outl, int R, int C){
  int idx = blockIdx.x * blockDim.x + threadIdx.x;
  if (idx < R * C){
    int r = idx / C, c = idx - r * C;
    float v = sane(in[idx]);
    _Float16 h = (_Float16)v;
    outh[(size_t)c * R + r] = h;
    outl[(size_t)c * R + r] = (_Float16)(v - (float)h);
  }
}

// transposed bf16 hi/lo split (slot head weights)
__global__ void k_wsplitbf(const float* __restrict__ in, __bf16* __restrict__ outh,
                           __bf16* __restrict__ outl, int R, int C){
  int idx = blockIdx.x * blockDim.x + threadIdx.x;
  if (idx < R * C){
    int r = idx / C, c = idx - r * C;
    float v = sane(in[idx]);
    __bf16 h = (__bf16)v;
    outh[(size_t)c * R + r] = h;
    outl[(size_t)c * R + r] = (__bf16)(v - (float)h);
  }
}

__global__ void k_transpose32(const float* __restrict__ in, float* __restrict__ out,
                              int R, int C){
  int idx = blockIdx.x * blockDim.x + threadIdx.x;
  if (idx < R * C){ int r = idx / C, c = idx - r * C; out[(size_t)c * R + r] = sane(in[idx]); }
}

__global__ void k_w35(const float* __restrict__ W3, const float* __restrict__ W4,
                      const float* __restrict__ b4, const float* __restrict__ W5,
                      float* __restrict__ w35, float* __restrict__ w45, float* __restrict__ b45){
  __shared__ float w5s[HID];
  int t = threadIdx.x;                     // block = 384
  w5s[t] = sane(W5[t]);
  __syncthreads();
  float s3 = 0.f, s4 = 0.f;
  for (int j = 0; j < HID; ++j){
    float w5 = w5s[j];
    s3 += sane(W3[(size_t)t * HID + j]) * w5;
    s4 += sane(W4[(size_t)t * HID + j]) * w5;
  }
  w35[t] = s3; w45[t] = s4;
  if (t == 0){
    float s = 0.f;
    for (int j = 0; j < HID; ++j) s += sane(b4[j]) * w5s[j];
    *b45 = s;
  }
}

// X0 = split(tanh(Cs)) — setup, vectorized
__global__ void k_prep(const float* __restrict__ Cs,
                       _Float16* __restrict__ X0h, _Float16* __restrict__ X0l){
  const size_t n4 = (size_t)MTOK * HID / 4;
  const size_t stride = (size_t)gridDim.x * blockDim.x;
  for (size_t i = blockIdx.x * (size_t)blockDim.x + threadIdx.x; i < n4; i += stride){
    f4 v = *(const f4*)(Cs + i * 4);
    h4v hh, ll;
#pragma unroll
    for (int j = 0; j < 4; ++j){
      float x = fast_tanh(sane(v[j]));
      _Float16 h = (_Float16)x;
      hh[j] = h; ll[j] = (_Float16)(x - (float)h);
    }
    *(h4v*)(X0h + i * 4) = hh;
    *(h4v*)(X0l + i * 4) = ll;
  }
}

__global__ void k_ci(const float* __restrict__ ci, float* __restrict__ r_inte){
  size_t i = blockIdx.x * (size_t)blockDim.x + threadIdx.x;
  if (i < (size_t)NB * HID) r_inte[i] = sane(ci[i]);
}

__global__ void k_hy(const float* __restrict__ Hm, const float* __restrict__ w45,
                     const float* __restrict__ b45, float* __restrict__ hy){
  int wave = threadIdx.x >> 6, lane = threadIdx.x & 63;
  int tok = blockIdx.x * 4 + wave;
  const float* row = Hm + (size_t)tok * HID;
  float s = 0.f;
#pragma unroll
  for (int i = 0; i < 6; ++i){ int k = lane + 64 * i; s += sane(row[k]) * w45[k]; }
  for (int off = 32; off; off >>= 1) s += __shfl_down(s, off);
  if (lane == 0) hy[tok] = clampf(s + *b45, -1e30f, 1e30f);
}

// ---------------- per-iteration small GEMMs (fp32) ----------------
template <int TANH>
__global__ void k_vecmat(const float* __restrict__ in, const float* __restrict__ Wt,
                         float* __restrict__ out, float* __restrict__ pre_store){
  const int b = blockIdx.x, t = threadIdx.x;   // block = 384
  __shared__ float v[HID];
  float x = in[(size_t)b * HID + t];
  if (TANH) x = fast_tanh(x);
  v[t] = x;
  if (pre_store) pre_store[(size_t)b * HID + t] = x;
  __syncthreads();
  const float* wr = Wt + (size_t)t * HID;
  float s = 0.f;
  for (int k = 0; k < HID; ++k) s += v[k] * wr[k];
  out[(size_t)b * HID + t] = clampf(s, -1e30f, 1e30f);
}

// ---------------- staged split-fp16 GEMM: P0 = X0 @ W0 (setup, copy staging) -----
__global__ void __launch_bounds__(256, 3) k_p0c(
    const _Float16* __restrict__ X0h, const _Float16* __restrict__ X0l,
    const _Float16* __restrict__ Wth, const _Float16* __restrict__ Wtl,
    const int* __restrict__ lens,
    _Float16* __restrict__ P0h, _Float16* __restrict__ P0l){
  __shared__ _Float16 Ah[128*APITCH], Al[128*APITCH], Bh[128*APITCH], Bl[128*APITCH];
  const int t = threadIdx.x;
  const int wave = t >> 6, lane = t & 63, quad = lane >> 4, lr = lane & 15;
  const int wm = wave & 1, wn = wave >> 1;
  const int bx = blockIdx.x, by = blockIdx.y;
  const int len = lens[bx];
  const bool live = (wm * 64) < len;
  f4 acc[4][4] = {};
  for (int kk = 0; kk < HID; kk += 32){
#pragma unroll
    for (int i = 0; i < 2; ++i){
      int tau = t + 256 * i;
      int row = tau >> 2, v8 = (tau & 3) << 3;
      size_t ga = ((size_t)(bx * 128 + row)) * HID + kk + v8;
      size_t gb = ((size_t)(by * 128 + row)) * HID + kk + v8;
      *(h8*)&Ah[row * APITCH + v8] = ldh(X0h + ga);
      *(h8*)&Al[row * APITCH + v8] = ldh(X0l + ga);
      *(h8*)&Bh[row * APITCH + v8] = ldh(Wth + gb);
      *(h8*)&Bl[row * APITCH + v8] = ldh(Wtl + gb);
    }
    __syncthreads();
    if (live){
      h8 ah[4], al[4];
#pragma unroll
      for (int mi = 0; mi < 4; ++mi){
        int r = (wm * 64 + mi * 16 + lr) * APITCH + quad * 8;
        ah[mi] = *(h8*)&Ah[r]; al[mi] = *(h8*)&Al[r];
      }
#pragma unroll
      for (int ni = 0; ni < 4; ++ni){
        int r = (wn * 64 + ni * 16 + lr) * APITCH + quad * 8;
        h8 bh = *(h8*)&Bh[r], bl = *(h8*)&Bl[r];
#pragma unroll
        for (int mi = 0; mi < 4; ++mi){
          acc[mi][ni] = mfma16h(ah[mi], bh, acc[mi][ni]);
          acc[mi][ni] = mfma16h(ah[mi], bl, acc[mi][ni]);
          acc[mi][ni] = mfma16h(al[mi], bh, acc[mi][ni]);
        }
      }
    }
    __syncthreads();
  }
  if (live){
#pragma unroll
    for (int ni = 0; ni < 4; ++ni){
      int col = by * 128 + wn * 64 + ni * 16 + lr;
#pragma unroll
      for (int mi = 0; mi < 4; ++mi)
#pragma unroll
        for (int r = 0; r < 4; ++r){
          int rl = wm * 64 + mi * 16 + quad * 4 + r;
          if (rl < len){
            size_t o = ((size_t)(bx * 128 + rl)) * HID + col;
            _Float16 h, l; split16(acc[mi][ni][r], &h, &l);
            P0h[o] = h; P0l[o] = l;
          }
        }
    }
  }
}

// ---------------- G2 (per iteration): 64 rows x full N=384 per block -------------
// A = T = tanh(P0 + yw1) computed ONCE during staging (T never in HBM, no by-
// redundancy); B-frags direct from L2 (W2 hi/lo = 590 KB, L2-resident);
// f = sigmoid(T @ W2); masked row-reduce of fusion_out -> atomicAdd S.
__global__ void __launch_bounds__(256, 2) k_g2n(
    const _Float16* __restrict__ P0h, const _Float16* __restrict__ P0l,
    const _Float16* __restrict__ Wth, const _Float16* __restrict__ Wtl,
    const float* __restrict__ yw1, const float* __restrict__ Cs,
    const float* __restrict__ y0b, const float* __restrict__ r_inte,
    const int* __restrict__ lens, float* __restrict__ S){
  __shared__ _Float16 Ah[64*APITCH], Al[64*APITCH];   // 10.2 KB
  const int t = threadIdx.x;
  const int wave = t >> 6, lane = t & 63, quad = lane >> 4, lr = lane & 15;
  const int bx = blockIdx.x;           // 64-row group (half sentence)
  const int b = bx >> 1;
  const int len = lens[b];
  const int row0 = (bx & 1) * 64;      // block's first row within sentence
  if (row0 >= len) return;             // whole block is padding: contributes 0 to S
  const int gr0 = bx * 64;             // global row base
  const int srow = t >> 2;             // staging: 4 threads/row, 8 K-els each
  const int sk8 = (t & 3) << 3;
  f4 acc[4][6] = {};
  for (int kk = 0; kk < HID; kk += 32){
    {   // A-stage: T = tanh(P0.hi + P0.lo + yw1), split to hi/lo planes
      size_t g = ((size_t)(gr0 + srow)) * HID + kk + sk8;
      h8 ph = ldh(P0h + g), pl = ldh(P0l + g);
      const float* yw = yw1 + (size_t)b * HID + kk + sk8;
      h8 th, tl;
#pragma unroll
      for (int j = 0; j < 8; ++j){
        float x = fast_tanh((float)ph[j] + (float)pl[j] + yw[j]);
        _Float16 h = (_Float16)x;
        th[j] = h; tl[j] = (_Float16)(x - (float)h);
      }
      *(h8*)&Ah[srow * APITCH + sk8] = th;
      *(h8*)&Al[srow * APITCH + sk8] = tl;
    }
    __syncthreads();
    h8 ah[4], al[4];
#pragma unroll
    for (int mi = 0; mi < 4; ++mi){
      int r = (mi * 16 + lr) * APITCH + quad * 8;
      ah[mi] = *(h8*)&Ah[r]; al[mi] = *(h8*)&Al[r];
    }
#pragma unroll
    for (int ni = 0; ni < 6; ++ni){
      size_t rb = ((size_t)(wave * 96 + ni * 16 + lr)) * HID + kk + quad * 8;
      h8 bh = ldh(Wth + rb), bl = ldh(Wtl + rb);   // L2-resident weights
#pragma unroll
      for (int mi = 0; mi < 4; ++mi){
        acc[mi][ni] = mfma16h(ah[mi], bh, acc[mi][ni]);
        acc[mi][ni] = mfma16h(ah[mi], bl, acc[mi][ni]);
        acc[mi][ni] = mfma16h(al[mi], bh, acc[mi][ni]);
      }
    }
    __syncthreads();
  }
  const float* yb = y0b + (size_t)b * HID;
  const float* rb = r_inte + (size_t)b * HID;
#pragma unroll
  for (int ni = 0; ni < 6; ++ni){
    const int col = wave * 96 + ni * 16 + lr;
    const float y0 = yb[col];
    const float yv = rb[col];
    float csum = 0.f;
#pragma unroll
    for (int mi = 0; mi < 4; ++mi)
#pragma unroll
      for (int r = 0; r < 4; ++r){
        const int rl = row0 + mi * 16 + quad * 4 + r;       // within sentence
        const int grow = gr0 + mi * 16 + quad * 4 + r;      // global token row
        const float f = sigmoid_c(acc[mi][ni][r]);
        const float omf = 1.f - f;
        const float xv = sane(Cs[(size_t)grow * HID + col]);
        const float x0 = fast_tanh(xv);
        const float outv = f * f * x0 + f * xv + omf * omf * y0 + omf * yv;
        csum += (rl < len) ? outv : 0.f;
      }
    csum += __shfl_xor(csum, 16);
    csum += __shfl_xor(csum, 32);
    if (quad == 0) atomicAdd(&S[(size_t)b * HID + col], csum);
  }
}

// ---------------- stage D: rates -> softmax -> f_inte -> r_inte (fp32) ----------------
__global__ void k_stageD(
    const float* __restrict__ Cs, const float* __restrict__ Hm,
    const float* __restrict__ ci,
    const float* __restrict__ fss, const float* __restrict__ w35,
    const float* __restrict__ hy, const int* __restrict__ lens,
    float* __restrict__ r_inte){
  const int b = blockIdx.x;
  const int t = threadIdx.x;            // 384 threads = 6 waves
  const int len = lens[b];
  __shared__ float fssw[HID];
  __shared__ float rates[SLEN];
  __shared__ float wA[SLEN], wB[SLEN], wC[SLEN], wD[SLEN];
  fssw[t] = fss[(size_t)b * HID + t] * w35[t];
  __syncthreads();
  const int wave = t >> 6, lane = t & 63;
  for (int l = wave; l < SLEN; l += 6){
    const float* row = Cs + ((size_t)b * SLEN + l) * HID;
    float s = 0.f;
#pragma unroll
    for (int i = 0; i < 6; ++i){ int k = lane + 64 * i; s += sane(row[k]) * fssw[k]; }
    for (int off = 32; off; off >>= 1) s += __shfl_down(s, off);
    if (lane == 0) rates[l] = clampf(s + hy[(size_t)b * SLEN + l], -1e30f, 1e30f);
  }
  __syncthreads();
  if (wave == 0){
    float r0 = (lane < len) ? rates[lane] : -3.0e38f;
    float r1 = (lane + 64 < len) ? rates[lane + 64] : -3.0e38f;
    float mx = fmaxf(r0, r1);
    for (int off = 32; off; off >>= 1) mx = fmaxf(mx, __shfl_xor(mx, off));
    float e0 = (lane < len) ? __expf(r0 - mx) : 0.f;
    float e1 = (lane + 64 < len) ? __expf(r1 - mx) : 0.f;
    float sm = e0 + e1;
    for (int off = 32; off; off >>= 1) sm += __shfl_xor(sm, off);
    const float inv = (sm > 0.f) ? (1.f / sm) : 0.f;
    float a0 = clampf(e0 * inv, 0.f, 1.f), a1 = clampf(e1 * inv, 0.f, 1.f);
    wA[lane] = a0 * a0; wB[lane] = a0; wC[lane] = (1.f - a0) * (1.f - a0); wD[lane] = 1.f - a0;
    wA[lane + 64] = a1 * a1; wB[lane + 64] = a1;
    wC[lane + 64] = (1.f - a1) * (1.f - a1); wD[lane + 64] = 1.f - a1;
  }
  __syncthreads();
  const float fs = fss[(size_t)b * HID + t];
  float acc = 0.f;
  for (int l = 0; l < len; ++l){
    const float cv = sane(Cs[((size_t)b * SLEN + l) * HID + t]);
    const float hv = sane(Hm[((size_t)b * SLEN + l) * HID + t]);
    const float rs = fs * cv;
    acc += wA[l] * fast_tanh(rs) + wB[l] * rs + wC[l] * fast_tanh(hv) + wD[l] * hv;
  }
  r_inte[(size_t)b * HID + t] = clampf(acc + sane(ci[(size_t)b * HID + t]), -1e30f, 1e30f);
}

// ---------------- output heads (fp32 outputs) ----------------
__global__ void k_intent(const float* __restrict__ r_inte, const float* __restrict__ Wit,
                         float* __restrict__ out){
  const int t = threadIdx.x;                 // block 128: 4 sentences x 32 labels
  const int b = blockIdx.x * 4 + (t >> 5);
  const int n = t & 31;
  const float* wr = Wit + (size_t)n * HID;
  const float* rr = r_inte + (size_t)b * HID;
  float s = 0.f;
  for (int k = 0; k < HID; ++k) s += rr[k] * wr[k];
  out[(size_t)b * NLAB + n] = clampf(s, -3e38f, 3e38f);
}

// slot_output = [H | fss(b).*c] @ W_slot, split-bf16 3-product, dead waves write 0.
__global__ void __launch_bounds__(256, 2) k_slot_bf(
    const float* __restrict__ Hm, const float* __restrict__ Cs,
    const float* __restrict__ fss, const int* __restrict__ lens,
    const __bf16* __restrict__ Wth, const __bf16* __restrict__ Wtl,
    float* __restrict__ out){
  const int wave = threadIdx.x >> 6, lane = threadIdx.x & 63;
  const int quad = lane >> 4, lr = lane & 15;
  const int m0 = blockIdx.x * 128 + (wave & 1) * 64;
  const int n0 = (wave >> 1) * 64;
  const int b = blockIdx.x;
  const int ko = quad * 8;
  const int len = lens[b];
  if ((wave & 1) * 64 >= len){
#pragma unroll
    for (int mi = 0; mi < 4; ++mi)
#pragma unroll
      for (int ni = 0; ni < 4; ++ni)
#pragma unroll
        for (int r = 0; r < 4; ++r){
          const int row = m0 + mi * 16 + quad * 4 + r;
          const int col = n0 + ni * 16 + lr;
          out[(size_t)row * NSLOT + col] = 0.f;
        }
    return;
  }
  f4 acc[4][4] = {};
  for (int kk = 0; kk < 2 * HID; kk += 32){
    b8 ah[4], al[4], bh[4], bl[4];
#pragma unroll
    for (int i = 0; i < 4; ++i){
      size_t rb = (size_t)(n0 + i * 16 + lr) * (2 * HID) + kk + ko;
      bh[i] = ldb(Wth + rb); bl[i] = ldb(Wtl + rb);
    }
    if (kk < HID){
#pragma unroll
      for (int i = 0; i < 4; ++i){
        const float* hrow = Hm + (size_t)(m0 + i * 16 + lr) * HID + kk + ko;
        b8 vh, vl;
#pragma unroll
        for (int j = 0; j < 8; ++j){
          float v = sane(hrow[j]);
          __bf16 h = (__bf16)v;
          vh[j] = h; vl[j] = (__bf16)(v - (float)h);
        }
        ah[i] = vh; al[i] = vl;
      }
    } else {
      const int k2 = kk - HID + ko;
      float fv[8];
#pragma unroll
      for (int j = 0; j < 8; ++j) fv[j] = fss[(size_t)b * HID + k2 + j];
#pragma unroll
      for (int i = 0; i < 4; ++i){
        const float* crow = Cs + (size_t)(m0 + i * 16 + lr) * HID + k2;
        b8 vh, vl;
#pragma unroll
        for (int j = 0; j < 8; ++j){
          float v = fv[j] * sane(crow[j]);
          __bf16 h = (__bf16)v;
          vh[j] = h; vl[j] = (__bf16)(v - (float)h);
        }
        ah[i] = vh; al[i] = vl;
      }
    }
#pragma unroll
    for (int mi = 0; mi < 4; ++mi)
#pragma unroll
      for (int ni = 0; ni < 4; ++ni){
        acc[mi][ni] = mfma16b(ah[mi], bh[ni], acc[mi][ni]);
        acc[mi][ni] = mfma16b(ah[mi], bl[ni], acc[mi][ni]);
        acc[mi][ni] = mfma16b(al[mi], bh[ni], acc[mi][ni]);
      }
  }
#pragma unroll
  for (int mi = 0; mi < 4; ++mi)
#pragma unroll
    for (int ni = 0; ni < 4; ++ni)
#pragma unroll
      for (int r = 0; r < 4; ++r){
        const int row = m0 + mi * 16 + quad * 4 + r;
        const int col = n0 + ni * 16 + lr;
        out[(size_t)row * NSLOT + col] = clampf(acc[mi][ni][r], -3e38f, 3e38f);
      }
}

// ---------------- launch ----------------
extern "C" void kernel_launch(void* const* d_in, const int* in_sizes, int n_in,
                              void* d_out, int out_size, void* d_ws, size_t ws_size,
                              hipStream_t stream){
  (void)in_sizes; (void)n_in; (void)out_size;
  const float* Hm  = (const float*)d_in[0];
  const float* Cs  = (const float*)d_in[1];
  const float* ci  = (const float*)d_in[2];
  const float* W0  = (const float*)d_in[3];
  const float* W1  = (const float*)d_in[4];
  const float* W2  = (const float*)d_in[5];
  const float* W3  = (const float*)d_in[6];
  const float* W4  = (const float*)d_in[7];
  const float* b4  = (const float*)d_in[8];
  const float* W5  = (const float*)d_in[9];
  const float* Vs  = (const float*)d_in[10];
  const float* Wi  = (const float*)d_in[11];
  const float* Wsl = (const float*)d_in[12];
  const int* lens_raw = (const int*)d_in[13];
  // d_in[14] = iteration_num = 3 (hard-coded)

  char* base = (char*)d_ws;
  size_t off = 0;
  auto alloc = [&](size_t bytes) -> void* {
    void* p = base + off; off += (bytes + 255) & ~(size_t)255; return p;
  };
  const size_t NT = (size_t)MTOK * HID;
  _Float16* X0h  = (_Float16*)alloc(NT * 2);
  _Float16* X0l  = (_Float16*)alloc(NT * 2);
  _Float16* P0h  = (_Float16*)alloc(NT * 2);
  _Float16* P0l  = (_Float16*)alloc(NT * 2);
  _Float16* W0th = (_Float16*)alloc((size_t)HID * HID * 2);
  _Float16* W0tl = (_Float16*)alloc((size_t)HID * HID * 2);
  _Float16* W2th = (_Float16*)alloc((size_t)HID * HID * 2);
  _Float16* W2tl = (_Float16*)alloc((size_t)HID * HID * 2);
  __bf16*   Wsth = (__bf16*)alloc((size_t)2 * HID * NSLOT * 2);
  __bf16*   Wstl = (__bf16*)alloc((size_t)2 * HID * NSLOT * 2);
  float* W1t    = (float*)alloc((size_t)HID * HID * 4);
  float* Vst    = (float*)alloc((size_t)HID * HID * 4);
  float* Wit    = (float*)alloc((size_t)HID * NLAB * 4);
  float* w35    = (float*)alloc(HID * 4);
  float* w45    = (float*)alloc(HID * 4);
  float* b45    = (float*)alloc(4);
  float* hy     = (float*)alloc((size_t)MTOK * 4);
  float* yw1    = (float*)alloc((size_t)NB * HID * 4);
  float* y0b    = (float*)alloc((size_t)NB * HID * 4);
  float* r_inte = (float*)alloc((size_t)NB * HID * 4);
  float* S      = (float*)alloc((size_t)NB * HID * 4);
  float* fss    = (float*)alloc((size_t)NB * HID * 4);
  int* lensN    = (int*)alloc((size_t)NB * 4);
  if (off > ws_size) return;

  k_lens<<<1, NB, 0, stream>>>(lens_raw, lensN);
  k_wsplit16<<<(HID * HID + 255) / 256, 256, 0, stream>>>(W0, W0th, W0tl, HID, HID);
  k_wsplit16<<<(HID * HID + 255) / 256, 256, 0, stream>>>(W2, W2th, W2tl, HID, HID);
  k_wsplitbf<<<(2 * HID * NSLOT + 255) / 256, 256, 0, stream>>>(Wsl, Wsth, Wstl, 2 * HID, NSLOT);
  k_transpose32<<<(HID * HID + 255) / 256, 256, 0, stream>>>(W1, W1t, HID, HID);
  k_transpose32<<<(HID * HID + 255) / 256, 256, 0, stream>>>(Vs, Vst, HID, HID);
  k_transpose32<<<(HID * NLAB + 255) / 256, 256, 0, stream>>>(Wi, Wit, HID, NLAB);
  k_w35<<<1, HID, 0, stream>>>(W3, W4, b4, W5, w35, w45, b45);
  k_ci<<<(NB * HID + 255) / 256, 256, 0, stream>>>(ci, r_inte);
  k_hy<<<MTOK / 4, 256, 0, stream>>>(Hm, w45, b45, hy);
  k_prep<<<4096, 256, 0, stream>>>(Cs, X0h, X0l);
  k_p0c<<<dim3(NB, 3), 256, 0, stream>>>(X0h, X0l, W0th, W0tl, lensN, P0h, P0l);

  for (int it = 0; it < 3; ++it){
    k_vecmat<1><<<NB, HID, 0, stream>>>(r_inte, W1t, yw1, y0b);
    hipMemsetAsync(S, 0, (size_t)NB * HID * 4, stream);
    k_g2n<<<MTOK / 64, 256, 0, stream>>>(P0h, P0l, W2th, W2tl, yw1, Cs, y0b, r_inte, lensN, S);
    k_vecmat<0><<<NB, HID, 0, stream>>>(S, Vst, fss, (float*)nullptr);
    k_stageD<<<NB, HID, 0, stream>>>(Cs, Hm, ci, fss, w35, hy, lensN, r_inte);
  }

  float* outp = (float*)d_out;
  k_intent<<<NB / 4, 128, 0, stream>>>(r_inte, Wit, outp);
  k_slot_bf<<<NB, 256, 0, stream>>>(Hm, Cs, fss, lensN, Wsth, Wstl, outp + (size_t)NB * NLAB);
}